// Round 7
// baseline (424.596 us; speedup 1.0000x reference)
//
#include <hip/hip_runtime.h>

// fp16 vector types for MFMA fragments
typedef _Float16 hf2 __attribute__((ext_vector_type(2)));
typedef _Float16 hf4 __attribute__((ext_vector_type(4)));
typedef _Float16 hf8 __attribute__((ext_vector_type(8)));
typedef float    fx4 __attribute__((ext_vector_type(4)));

// async global->LDS, 16B per lane; LDS dest must be lane-linear (base + lane*16)
#define GLD16(gp, lp) __builtin_amdgcn_global_load_lds(                      \
    (const __attribute__((address_space(1))) void*)(gp),                     \
    (__attribute__((address_space(3))) void*)(lp), 16, 0, 0)

// ---------------- f32 -> f16 conversion ----------------
__global__ __launch_bounds__(256) void cvt_x_k(const float* __restrict__ s,
                                               _Float16* __restrict__ d) {
  size_t i = (size_t)blockIdx.x * 256 + threadIdx.x;  // grid 4096 -> 1,048,576 float4s
  float4 v = ((const float4*)s)[i];
  hf4 o = {(_Float16)v.x, (_Float16)v.y, (_Float16)v.z, (_Float16)v.w};
  *(hf4*)(d + 4 * i) = o;
}

__global__ __launch_bounds__(256) void cvt_w_k(const float* __restrict__ s0,
                                               const float* __restrict__ s1,
                                               const float* __restrict__ s2,
                                               const float* __restrict__ s3,
                                               _Float16* __restrict__ d) {
  const float* s = blockIdx.y == 0 ? s0 : blockIdx.y == 1 ? s1 : blockIdx.y == 2 ? s2 : s3;
  size_t i = (size_t)blockIdx.x * 256 + threadIdx.x;  // grid.x 1024 -> 262,144 float4s
  float4 v = ((const float4*)s)[i];
  hf4 o = {(_Float16)v.x, (_Float16)v.y, (_Float16)v.z, (_Float16)v.w};
  *(hf4*)(d + (size_t)blockIdx.y * 1048576 + 4 * i) = o;
}

// ---------------- 128x128 tile GEMM, C = A[M,1024] * B[N,1024]^T + bias ----------------
__device__ __forceinline__ void gemm_tile(
    const _Float16* __restrict__ A, const _Float16* __restrict__ B,
    const float* __restrict__ bias, _Float16* __restrict__ Ch,
    float* __restrict__ Cf, int m0, int n0, int ldc, int mode)
{
  __shared__ alignas(16) _Float16 Asm[2][128 * 32];
  __shared__ alignas(16) _Float16 Bsm[2][128 * 32];
  const int tid = (int)threadIdx.x;
  const int lane = tid & 63, wv = tid >> 6;
  const int col = lane & 15, g = lane >> 4;

  fx4 acc[2][8];
#pragma unroll
  for (int i = 0; i < 2; ++i)
#pragma unroll
    for (int j = 0; j < 8; ++j) acc[i][j] = fx4{0.f, 0.f, 0.f, 0.f};

  const int cp0 = tid, cp1 = tid + 256;
  const int row0 = cp0 >> 2, row1 = cp1 >> 2;
  const int ch0 = (cp0 & 3) ^ ((row0 >> 1) & 3);
  const int ch1 = (cp1 & 3) ^ ((row1 >> 1) & 3);
  const _Float16* a0 = A + (size_t)(m0 + row0) * 1024 + ch0 * 8;
  const _Float16* a1 = A + (size_t)(m0 + row1) * 1024 + ch1 * 8;
  const _Float16* b0 = B + (size_t)(n0 + row0) * 1024 + ch0 * 8;
  const _Float16* b1 = B + (size_t)(n0 + row1) * 1024 + ch1 * 8;

  int aoff[2], boff[8];
#pragma unroll
  for (int mi = 0; mi < 2; ++mi) {
    int row = wv * 32 + mi * 16 + col;
    aoff[mi] = (row * 4 + (g ^ ((row >> 1) & 3))) * 8;
  }
#pragma unroll
  for (int nj = 0; nj < 8; ++nj) {
    int row = nj * 16 + col;
    boff[nj] = (row * 4 + (g ^ ((row >> 1) & 3))) * 8;
  }

#define STAGE_T(bufi, kt) {                          \
    GLD16(a0 + (kt) * 32, &Asm[bufi][cp0 * 8]);      \
    GLD16(a1 + (kt) * 32, &Asm[bufi][cp1 * 8]);      \
    GLD16(b0 + (kt) * 32, &Bsm[bufi][cp0 * 8]);      \
    GLD16(b1 + (kt) * 32, &Bsm[bufi][cp1 * 8]); }

  STAGE_T(0, 0);
  int buf = 0;
  for (int kt = 0; kt < 32; ++kt) {
    __syncthreads();
    if (kt + 1 < 32) STAGE_T(buf ^ 1, kt + 1);
    hf8 af[2], bf[8];
#pragma unroll
    for (int mi = 0; mi < 2; ++mi) af[mi] = *(const hf8*)&Asm[buf][aoff[mi]];
#pragma unroll
    for (int nj = 0; nj < 8; ++nj) bf[nj] = *(const hf8*)&Bsm[buf][boff[nj]];
#pragma unroll
    for (int mi = 0; mi < 2; ++mi)
#pragma unroll
      for (int nj = 0; nj < 8; ++nj)
        acc[mi][nj] = __builtin_amdgcn_mfma_f32_16x16x32_f16(af[mi], bf[nj], acc[mi][nj], 0, 0, 0);
    buf ^= 1;
  }
#undef STAGE_T

  if (mode == 2) {
#pragma unroll
    for (int nj = 0; nj < 8; ++nj) {
      float bn = bias[n0 + nj * 16 + col];
#pragma unroll
      for (int mi = 0; mi < 2; ++mi)
#pragma unroll
        for (int r = 0; r < 4; ++r)
          Cf[(size_t)(m0 + wv * 32 + mi * 16 + 4 * g + r) * ldc + n0 + nj * 16 + col] =
              acc[mi][nj][r] + bn;
    }
  } else if (mode == 0) {
#pragma unroll
    for (int nj = 0; nj < 8; ++nj) {
      float bn = bias[n0 + nj * 16 + col];
#pragma unroll
      for (int mi = 0; mi < 2; ++mi)
#pragma unroll
        for (int r = 0; r < 4; ++r)
          Ch[(size_t)(m0 + wv * 32 + mi * 16 + 4 * g + r) * ldc + n0 + nj * 16 + col] =
              (_Float16)(acc[mi][nj][r] + bn);
    }
  } else {  // mode 1: bias over m
#pragma unroll
    for (int mi = 0; mi < 2; ++mi)
#pragma unroll
      for (int r = 0; r < 4; ++r) {
        float bm = bias[m0 + wv * 32 + mi * 16 + 4 * g + r];
#pragma unroll
        for (int nj = 0; nj < 8; ++nj)
          Ch[(size_t)(m0 + wv * 32 + mi * 16 + 4 * g + r) * ldc + n0 + nj * 16 + col] =
              (_Float16)(acc[mi][nj][r] + bm);
      }
  }
}

// QKV: blocks 0..255 -> Q, 256..511 -> K, 512..767 -> Vt (A=Wv, B=x -> transposed out)
__global__ __launch_bounds__(256, 3) void qkv_gemm_k(
    const _Float16* __restrict__ xh, const _Float16* __restrict__ Wqh,
    const _Float16* __restrict__ Wkh, const _Float16* __restrict__ Wvh,
    const float* __restrict__ bq, const float* __restrict__ bk,
    const float* __restrict__ bv, _Float16* __restrict__ Qh,
    _Float16* __restrict__ Kh, _Float16* __restrict__ Vt)
{
  int id = (int)blockIdx.x;
  if (id < 512) {
    int t = id & 255;
    const _Float16* Bp = (id < 256) ? Wqh : Wkh;
    const float*    bp = (id < 256) ? bq : bk;
    _Float16*       Cp = (id < 256) ? Qh : Kh;
    gemm_tile(xh, Bp, bp, Cp, nullptr, (t >> 3) * 128, (t & 7) * 128, 1024, 0);
  } else {
    int t = id - 512;  // M=1024 (e), N=4096 (b*s)
    gemm_tile(Wvh, xh, bv, Vt, nullptr, (t >> 5) * 128, (t & 31) * 128, 4096, 1);
  }
}

__global__ __launch_bounds__(256, 3) void out_gemm_k(
    const _Float16* __restrict__ Oh, const _Float16* __restrict__ Woh,
    const float* __restrict__ bo, float* __restrict__ outp)
{
  int id = (int)blockIdx.x;
  gemm_tile(Oh, Woh, bo, nullptr, outp, (id >> 3) * 128, (id & 7) * 128, 1024, 2);
}

// ---------------- fused attention: QK^T + heads-softmax + attn store + PV ----------------
// Grid 512, 8 waves. WG owns [16 q] x [1024 k half] (kh = k-split of 2), all 16 heads.
// Per 128-k chunk kc (8 chunks):
//   QK: per head h, stage K[128k][64d] + Q[16q][64d] fp16 via GLD16 (16B-chunk XOR
//       swizzle on the GLOBAL source, LDS dest lane-linear), double-buffered over h;
//       swapped QK^T (mfma(K,Q)) -> lane (col,g) holds all 16 head logits for
//       (q=q0+col, k=kchunk+16wv+4g+r).
//   softmax over h per lane -> P.
//   P->f16 into plds[16h][16q][132k] (REUSES the K/Q staging LDS; union - never
//       both live). Then: attn f32 nontemporal stores straight from plds (512B
//       contiguous runs), and PV: wave owns heads {wv, wv+8}, A-frag from plds,
//       B-frag = 8B direct loads from L2-hot Vt; acc accumulates across chunks.
// End: acc -> Opart[kh] fp16 partials (16MB, L2-local); reducer adds the 2 halves.
// XCD swizzle: xcd=id&7 -> (b, q-quarter); j=id>>3: kh outer / qy inner.
__global__ __launch_bounds__(512, 4) void attn_fused2_k(
    const _Float16* __restrict__ Qh, const _Float16* __restrict__ Kh,
    const _Float16* __restrict__ Vt, float* __restrict__ attnp,
    _Float16* __restrict__ Opart)
{
  const int tid = (int)threadIdx.x;
  const int lane = tid & 63, wv = tid >> 6;
  const int col = lane & 15, g = lane >> 4;

  const int id = (int)blockIdx.x;
  const int xcd = id & 7, j = id >> 3;          // j: 0..63
  const int b = xcd >> 2, qq = xcd & 3;         // batch, q-quarter
  const int kh = j >> 5, qyl = j & 31;          // k-half outer, qy inner
  const int q0 = (qq * 32 + qyl) * 16;

  // LDS union: staging (Kt 32KB + Qt 4KB) and plds (66KB) are never live together
  __shared__ alignas(16) char smem[67584];
  _Float16* Kt   = (_Float16*)smem;             // [2][128][64]
  _Float16* Qt   = (_Float16*)(smem + 32768);   // [2][16][64]
  _Float16* plds = (_Float16*)smem;             // [16][16][132]

  const _Float16* Qbase = Qh + (size_t)(b * 2048 + q0) * 1024;

  // staging slots: K 1024 x 16B (2/thread), Q 128 x 16B (threads 0..127)
  const int kr0 = tid >> 3,         kc0 = tid & 7;
  const int kr1 = (tid + 512) >> 3, kc1 = (tid + 512) & 7;
  const int qr = tid >> 3,          qc = tid & 7;

#define STAGE_H(bufi, h) {                                                    \
    GLD16(Kbase + (size_t)kr0 * 1024 + (h) * 64 + (kc0 ^ (kr0 & 7)) * 8,      \
          Kt + (bufi) * 8192 + tid * 8);                                      \
    GLD16(Kbase + (size_t)kr1 * 1024 + (h) * 64 + (kc1 ^ (kr1 & 7)) * 8,      \
          Kt + (bufi) * 8192 + (tid + 512) * 8);                              \
    if (tid < 128)                                                            \
      GLD16(Qbase + (size_t)qr * 1024 + (h) * 64 + (qc ^ (qr & 7)) * 8,       \
            Qt + (bufi) * 1024 + tid * 8);                                    \
  }

  fx4 acc[2][4];
#pragma unroll
  for (int i = 0; i < 2; ++i)
#pragma unroll
    for (int dt = 0; dt < 4; ++dt) acc[i][dt] = fx4{0.f, 0.f, 0.f, 0.f};

  float* attnbase = attnp + (size_t)(b * 16) * 2048 * 2048;
  const int krow = wv * 16 + col;
  const int srow = 2 * wv + (lane >> 5);   // attn-store row (0..15)
  const int sks  = (lane & 31) * 4;        // attn-store k offset (0..124)

  for (int kc = 0; kc < 8; ++kc) {
    const int kg = kh * 1024 + kc * 128;   // global k offset of this chunk
    const _Float16* Kbase = Kh + (size_t)(b * 2048 + kg) * 1024;

    fx4 lg[16];
#pragma unroll
    for (int h = 0; h < 16; ++h) lg[h] = fx4{0.f, 0.f, 0.f, 0.f};

    // ---- QK over 16 heads, double-buffered staging ----
    STAGE_H(0, 0);
    int buf = 0;
#pragma unroll
    for (int h = 0; h < 16; ++h) {
      __syncthreads();
      if (h < 15) STAGE_H(buf ^ 1, h + 1);
      hf8 ka0 = *(const hf8*)&Kt[buf * 8192 + krow * 64 + ((0 + g) ^ (krow & 7)) * 8];
      hf8 ka1 = *(const hf8*)&Kt[buf * 8192 + krow * 64 + ((4 + g) ^ (krow & 7)) * 8];
      hf8 qa0 = *(const hf8*)&Qt[buf * 1024 + col * 64 + ((0 + g) ^ (col & 7)) * 8];
      hf8 qa1 = *(const hf8*)&Qt[buf * 1024 + col * 64 + ((4 + g) ^ (col & 7)) * 8];
      lg[h] = __builtin_amdgcn_mfma_f32_16x16x32_f16(ka0, qa0, lg[h], 0, 0, 0);
      lg[h] = __builtin_amdgcn_mfma_f32_16x16x32_f16(ka1, qa1, lg[h], 0, 0, 0);
      buf ^= 1;
    }

    // ---- softmax over heads, per lane; element r <-> (q=q0+col, k=kg+16wv+4g+r)
    fx4 mx = lg[0];
#pragma unroll
    for (int h = 1; h < 16; ++h)
#pragma unroll
      for (int r = 0; r < 4; ++r) mx[r] = fmaxf(mx[r], lg[h][r]);
    fx4 sm = fx4{0.f, 0.f, 0.f, 0.f};
#pragma unroll
    for (int h = 0; h < 16; ++h)
#pragma unroll
      for (int r = 0; r < 4; ++r) {
        float p = __expf((lg[h][r] - mx[r]) * 0.125f);
        lg[h][r] = p;
        sm[r] += p;
      }
#pragma unroll
    for (int r = 0; r < 4; ++r) sm[r] = 1.f / sm[r];

    // ---- P (f16) into plds; wait for all waves done reading Kt/Qt first
    __syncthreads();
#pragma unroll
    for (int h = 0; h < 16; ++h) {
      hf4 pk = {(_Float16)(lg[h][0] * sm[0]), (_Float16)(lg[h][1] * sm[1]),
                (_Float16)(lg[h][2] * sm[2]), (_Float16)(lg[h][3] * sm[3])};
      *(hf4*)&plds[(h * 16 + col) * 132 + wv * 16 + 4 * g] = pk;
    }
    __syncthreads();

    // ---- attn f32 nontemporal stores from plds (512B contiguous per instr)
#pragma unroll
    for (int h = 0; h < 16; ++h) {
      hf4 v = *(const hf4*)&plds[(h * 16 + srow) * 132 + sks];
      fx4 o = {(float)v[0], (float)v[1], (float)v[2], (float)v[3]};
      __builtin_nontemporal_store(
          o, (fx4*)(attnbase + (size_t)(h * 2048 + q0 + srow) * 2048 + kg + sks));
    }

    // ---- PV: wave owns heads {wv, wv+8}; V direct from L2-hot Vt
#pragma unroll
    for (int hh = 0; hh < 2; ++hh) {
      const int h = wv + hh * 8;
      const _Float16* vb0 = Vt + (size_t)(h * 64 + col) * 4096 + b * 2048 + kg + 4 * g;
#pragma unroll
      for (int ks = 0; ks < 8; ++ks) {
        hf4 pa = *(const hf4*)&plds[(h * 16 + col) * 132 + ks * 16 + 4 * g];
#pragma unroll
        for (int dt = 0; dt < 4; ++dt) {
          hf4 vb = *(const hf4*)(vb0 + (size_t)dt * 16 * 4096 + ks * 16);
          acc[hh][dt] = __builtin_amdgcn_mfma_f32_16x16x16f16(pa, vb, acc[hh][dt], 0, 0, 0);
        }
      }
    }
    __syncthreads();  // protect plds before next chunk's staging overwrites it
  }
#undef STAGE_H

  // ---- write partial O (this k-half) as fp16
  _Float16* Op = Opart + (size_t)kh * 4194304;
#pragma unroll
  for (int hh = 0; hh < 2; ++hh) {
    const int h = wv + hh * 8;
#pragma unroll
    for (int dt = 0; dt < 4; ++dt)
#pragma unroll
      for (int r = 0; r < 4; ++r)
        Op[(size_t)(b * 2048 + q0 + 4 * g + r) * 1024 + h * 64 + dt * 16 + col] =
            (_Float16)acc[hh][dt][r];
  }
}

// ---------------- reduce the two k-half partials into Oh ----------------
__global__ __launch_bounds__(256) void red_o_k(const _Float16* __restrict__ p,
                                               _Float16* __restrict__ Oh) {
  size_t i = (size_t)blockIdx.x * 256 + threadIdx.x;  // grid 2048 -> 524288 hf8s
  hf8 a = ((const hf8*)p)[i];
  hf8 c = ((const hf8*)(p + 4194304))[i];
  hf8 o;
#pragma unroll
  for (int r = 0; r < 8; ++r) o[r] = (_Float16)((float)a[r] + (float)c[r]);
  ((hf8*)Oh)[i] = o;
}

// ---------------- launcher ----------------
extern "C" void kernel_launch(void* const* d_in, const int* in_sizes, int n_in,
                              void* d_out, int out_size, void* d_ws, size_t ws_size,
                              hipStream_t stream) {
  (void)in_sizes; (void)n_in; (void)out_size; (void)ws_size;
  const float* x  = (const float*)d_in[0];
  const float* Wq = (const float*)d_in[1];
  const float* bq = (const float*)d_in[2];
  const float* Wk = (const float*)d_in[3];
  const float* bk = (const float*)d_in[4];
  const float* Wv = (const float*)d_in[5];
  const float* bv = (const float*)d_in[6];
  const float* Wo = (const float*)d_in[7];
  const float* bo = (const float*)d_in[8];

  char* ws = (char*)d_ws;                           // layout (MB offsets):
  _Float16* xh   = (_Float16*)(ws + (0ull  << 20)); // 0..8    x fp16 [4096][1024]
  _Float16* Wqh  = (_Float16*)(ws + (8ull  << 20)); // 8..10
  _Float16* Wkh  = (_Float16*)(ws + (10ull << 20)); // 10..12
  _Float16* Wvh  = (_Float16*)(ws + (12ull << 20)); // 12..14
  _Float16* Woh  = (_Float16*)(ws + (14ull << 20)); // 14..16
  _Float16* Qh   = (_Float16*)(ws + (16ull << 20)); // 16..24  Q fp16 [4096][1024]
  _Float16* Kh   = (_Float16*)(ws + (24ull << 20)); // 24..32  K fp16
  _Float16* Vt   = (_Float16*)(ws + (32ull << 20)); // 32..40  V^T fp16 [1024][4096]
  _Float16* Oh   = (_Float16*)(ws + (40ull << 20)); // 40..48  attn-out fp16 [4096][1024]
  _Float16* Opart= (_Float16*)(ws + (48ull << 20)); // 48..64  O partials [2][4096][1024] f16

  float* outp  = (float*)d_out;
  float* attnp = outp + 4194304ull;  // attn region [2][16][2048][2048] f32

  cvt_x_k<<<4096, 256, 0, stream>>>(x, xh);
  cvt_w_k<<<dim3(1024, 4), 256, 0, stream>>>(Wq, Wk, Wv, Wo, Wqh);
  qkv_gemm_k<<<768, 256, 0, stream>>>(xh, Wqh, Wkh, Wvh, bq, bk, bv, Qh, Kh, Vt);
  attn_fused2_k<<<512, 512, 0, stream>>>(Qh, Kh, Vt, attnp, Opart);
  red_o_k<<<2048, 256, 0, stream>>>(Opart, Oh);
  out_gemm_k<<<256, 256, 0, stream>>>(Oh, Woh, bo, outp);
}